// Round 1
// baseline (679.577 us; speedup 1.0000x reference)
//
#include <hip/hip_runtime.h>
#include <hip/hip_bf16.h>

using short8 = __attribute__((ext_vector_type(8))) short;
using f32x4  = __attribute__((ext_vector_type(4))) float;
using u16x4  = __attribute__((ext_vector_type(4))) unsigned short;

#define THREADS 256
#define BM 64

// XOR-swizzled LDS byte offset for a [64][128] bf16 tile (row stride 256 B).
// Breaks the 16-way bank conflict on ds_read_b128 column reads (guide G4).
__device__ __forceinline__ int swz(int row, int byteInRow) {
    return (row * 256 + byteInRow) ^ ((row & 7) << 4);
}

// Split f32 into hi (truncated bf16) + lo (bf16 of residual).
// x = hi + lo + r, |r| <~ 2^-16 |x|.
__device__ __forceinline__ void split2(float x, unsigned short& hi, unsigned short& lo) {
    unsigned xb = __float_as_uint(x);
    hi = (unsigned short)(xb >> 16);
    float hf = __uint_as_float(xb & 0xFFFF0000u);
    float r  = x - hf;                    // exact
    lo = (unsigned short)(__float_as_uint(r) >> 16);
}

// shifted softplus: ln(0.5*(1+e^x))  (inputs bounded ~N(0,1)-scale dots; no overflow risk)
__device__ __forceinline__ float ssp(float x) {
    return __logf(0.5f * (1.0f + __expf(x)));
}

// Pre-split + transpose weights into ws:
// layout (ushort): [w1t_hi 16384][w1t_lo 16384][w2t_hi 16384][w2t_lo 16384]
// Wt[n][k] so a B-fragment (lane reads 8 consecutive k at column n) is one 16B load.
__global__ void prep_weights(const float* __restrict__ W1, const float* __restrict__ W2,
                             unsigned short* __restrict__ ws) {
    int idx = blockIdx.x * THREADS + threadIdx.x;     // 0..32767
    const float* W = (idx < 16384) ? W1 : W2;
    unsigned short* hi = ws + ((idx < 16384) ? 0 : 32768);
    unsigned short* lo = hi + 16384;
    int e = idx & 16383;
    int k = e >> 7, n = e & 127;
    unsigned short h, l;
    split2(W[e], h, l);
    hi[n * 128 + k] = h;
    lo[n * 128 + k] = l;
}

__global__ __launch_bounds__(THREADS, 2)
void fused_kernel(const float* __restrict__ dijk,
                  const float* __restrict__ b1,
                  const float* __restrict__ b2,
                  const int* __restrict__ seg,
                  const unsigned short* __restrict__ w1h,
                  const unsigned short* __restrict__ w1l,
                  const unsigned short* __restrict__ w2h,
                  const unsigned short* __restrict__ w2l,
                  float* __restrict__ out) {
    __shared__ __align__(16) unsigned short Ahi[BM * 128];  // 16 KB
    __shared__ __align__(16) unsigned short Alo[BM * 128];
    __shared__ __align__(16) unsigned short Hhi[BM * 128];
    __shared__ __align__(16) unsigned short Hlo[BM * 128];
    __shared__ int segs[BM];

    const int tid  = threadIdx.x;
    const int row0 = blockIdx.x * BM;

    if (tid < BM) segs[tid] = seg[row0 + tid];

    // ---- stage + split A tile: 64 x 128 f32 -> hi/lo bf16 in LDS (swizzled) ----
    for (int i = tid; i < BM * 32; i += THREADS) {
        int r  = i >> 5;        // row 0..63
        int c4 = i & 31;        // float4 index within row
        f32x4 v = *(const f32x4*)(dijk + (size_t)(row0 + r) * 128 + c4 * 4);
        u16x4 hi, lo;
#pragma unroll
        for (int e = 0; e < 4; ++e) {
            unsigned short hh, ll;
            split2(v[e], hh, ll);
            hi[e] = hh; lo[e] = ll;
        }
        int boff = swz(r, c4 * 8);
        *(u16x4*)((char*)Ahi + boff) = hi;
        *(u16x4*)((char*)Alo + boff) = lo;
    }
    __syncthreads();

    const int lane = tid & 63;
    const int w    = tid >> 6;   // wave 0..3 -> owns cols 32w..32w+31
    const int ln   = lane & 15;
    const int lg   = lane >> 4;

    // =========================== GEMM1: h = ssp(A @ W1 + b1) ===========================
    f32x4 acc[4][2];
#pragma unroll
    for (int mf = 0; mf < 4; ++mf)
#pragma unroll
        for (int nf = 0; nf < 2; ++nf)
            acc[mf][nf] = f32x4{0.f, 0.f, 0.f, 0.f};

#pragma unroll
    for (int ks = 0; ks < 4; ++ks) {
        short8 a_hi[4], a_lo[4];
#pragma unroll
        for (int mf = 0; mf < 4; ++mf) {
            int boff = swz(16 * mf + ln, 64 * ks + 16 * lg);
            a_hi[mf] = *(const short8*)((const char*)Ahi + boff);
            a_lo[mf] = *(const short8*)((const char*)Alo + boff);
        }
        short8 b_hi[2], b_lo[2];
#pragma unroll
        for (int nf = 0; nf < 2; ++nf) {
            int off = (32 * w + 16 * nf + ln) * 128 + 32 * ks + 8 * lg;  // ushort idx
            b_hi[nf] = *(const short8*)(w1h + off);
            b_lo[nf] = *(const short8*)(w1l + off);
        }
#pragma unroll
        for (int mf = 0; mf < 4; ++mf)
#pragma unroll
            for (int nf = 0; nf < 2; ++nf) {
                acc[mf][nf] = __builtin_amdgcn_mfma_f32_16x16x32_bf16(a_hi[mf], b_hi[nf], acc[mf][nf], 0, 0, 0);
                acc[mf][nf] = __builtin_amdgcn_mfma_f32_16x16x32_bf16(a_hi[mf], b_lo[nf], acc[mf][nf], 0, 0, 0);
                acc[mf][nf] = __builtin_amdgcn_mfma_f32_16x16x32_bf16(a_lo[mf], b_hi[nf], acc[mf][nf], 0, 0, 0);
            }
    }

    // epilogue 1: bias + ssp, split to hi/lo, store to LDS (A-frag layout for GEMM2)
    float bias1[2];
#pragma unroll
    for (int nf = 0; nf < 2; ++nf) bias1[nf] = b1[32 * w + 16 * nf + ln];

#pragma unroll
    for (int mf = 0; mf < 4; ++mf)
#pragma unroll
        for (int nf = 0; nf < 2; ++nf) {
            int col = 32 * w + 16 * nf + ln;
#pragma unroll
            for (int j = 0; j < 4; ++j) {
                float h = ssp(acc[mf][nf][j] + bias1[nf]);
                unsigned short hh, hl;
                split2(h, hh, hl);
                int row  = 16 * mf + 4 * lg + j;   // C/D layout: row=(lane>>4)*4+j
                int boff = swz(row, col * 2);
                *(unsigned short*)((char*)Hhi + boff) = hh;
                *(unsigned short*)((char*)Hlo + boff) = hl;
            }
        }
    __syncthreads();

    // =========================== GEMM2: w = ssp(h @ W2 + b2) ===========================
    f32x4 acc2[4][2];
#pragma unroll
    for (int mf = 0; mf < 4; ++mf)
#pragma unroll
        for (int nf = 0; nf < 2; ++nf)
            acc2[mf][nf] = f32x4{0.f, 0.f, 0.f, 0.f};

#pragma unroll
    for (int ks = 0; ks < 4; ++ks) {
        short8 a_hi[4], a_lo[4];
#pragma unroll
        for (int mf = 0; mf < 4; ++mf) {
            int boff = swz(16 * mf + ln, 64 * ks + 16 * lg);
            a_hi[mf] = *(const short8*)((const char*)Hhi + boff);
            a_lo[mf] = *(const short8*)((const char*)Hlo + boff);
        }
        short8 b_hi[2], b_lo[2];
#pragma unroll
        for (int nf = 0; nf < 2; ++nf) {
            int off = (32 * w + 16 * nf + ln) * 128 + 32 * ks + 8 * lg;
            b_hi[nf] = *(const short8*)(w2h + off);
            b_lo[nf] = *(const short8*)(w2l + off);
        }
#pragma unroll
        for (int mf = 0; mf < 4; ++mf)
#pragma unroll
            for (int nf = 0; nf < 2; ++nf) {
                acc2[mf][nf] = __builtin_amdgcn_mfma_f32_16x16x32_bf16(a_hi[mf], b_hi[nf], acc2[mf][nf], 0, 0, 0);
                acc2[mf][nf] = __builtin_amdgcn_mfma_f32_16x16x32_bf16(a_hi[mf], b_lo[nf], acc2[mf][nf], 0, 0, 0);
                acc2[mf][nf] = __builtin_amdgcn_mfma_f32_16x16x32_bf16(a_lo[mf], b_hi[nf], acc2[mf][nf], 0, 0, 0);
            }
    }

    // epilogue 2: bias + ssp, run-length merge over the 4 consecutive rows per frag, atomicAdd
    float bias2[2];
#pragma unroll
    for (int nf = 0; nf < 2; ++nf) bias2[nf] = b2[32 * w + 16 * nf + ln];

#pragma unroll
    for (int mf = 0; mf < 4; ++mf)
#pragma unroll
        for (int nf = 0; nf < 2; ++nf) {
            int col   = 32 * w + 16 * nf + ln;
            int rbase = 16 * mf + 4 * lg;
            float runv  = 0.f;
            int   runsg = -1;
#pragma unroll
            for (int j = 0; j < 4; ++j) {
                float v = ssp(acc2[mf][nf][j] + bias2[nf]);
                int   s = segs[rbase + j];
                if (j == 0) { runv = v; runsg = s; }
                else if (s == runsg) { runv += v; }
                else {
                    atomicAdd(out + (size_t)runsg * 128 + col, runv);
                    runv = v; runsg = s;
                }
            }
            atomicAdd(out + (size_t)runsg * 128 + col, runv);
        }
}

extern "C" void kernel_launch(void* const* d_in, const int* in_sizes, int n_in,
                              void* d_out, int out_size, void* d_ws, size_t ws_size,
                              hipStream_t stream) {
    (void)n_in; (void)ws_size;
    const float* dijk = (const float*)d_in[0];
    const float* W1   = (const float*)d_in[1];
    const float* b1   = (const float*)d_in[2];
    const float* W2   = (const float*)d_in[3];
    const float* b2   = (const float*)d_in[4];
    const int*   seg  = (const int*)d_in[5];
    float* out = (float*)d_out;
    unsigned short* wsp = (unsigned short*)d_ws;

    // out is poisoned 0xAA before every call -> zero it (atomic accumulation target)
    hipMemsetAsync(d_out, 0, (size_t)out_size * sizeof(float), stream);

    prep_weights<<<128, THREADS, 0, stream>>>(W1, W2, wsp);

    int rows = in_sizes[0] / 128;     // 600000
    int nblk = rows / BM;             // 9375 (exact)
    fused_kernel<<<nblk, THREADS, 0, stream>>>(dijk, b1, b2, seg,
                                               wsp, wsp + 16384, wsp + 32768, wsp + 49152,
                                               out);
}